// Round 7
// baseline (146.653 us; speedup 1.0000x reference)
//
#include <hip/hip_runtime.h>
#include <stdint.h>

// DepthAwareConv2d: out = conv2d(x * depth, weight, pad=1) + bias
// (depth is channel-independent, so the depth-modulated im2col GEMM factors
//  into a plain 3x3 conv of xd = x*depth).
//
// R7: occupancy fix. R6 was wave-starved: acc[4][8] (128 AGPR) + 128 VGPR
//     ~= 256 regs/wave -> 2 waves/SIMD; no pipe >40% busy. Now 512-thread
//     blocks, 8 waves (2 wm x 4 wn), wave tile 64o x 64px, acc[4][4] (64) +
//     a ping-pong (32) + b (16) ~= 120 regs -> __launch_bounds__(512,4) =
//     4 waves/SIMD, 16 waves/CU. Same block tile (128o x 256px), same strip
//     staging (33,280 B), same wt2 fragment-major A stream, same 8 barriers.
//     Per-CU pipe totals unchanged; only latency hiding doubles.

#define C_IN 128
#define O_OUT 256
#define HW 128
#define NB 4
#define PADW 130

#define XD_ELEMS ((size_t)NB * PADW * PADW * C_IN)
#define XD_BYTES (XD_ELEMS * 2)          // 17,305,600 B
#define WT_ELEMS ((size_t)O_OUT * C_IN * 9)
#define WT_BYTES (WT_ELEMS * 2)          // 589,824 B

typedef __attribute__((ext_vector_type(8))) short short8;  // 8 bf16 (4 VGPRs)
typedef __attribute__((ext_vector_type(4))) float f32x4;
typedef __attribute__((ext_vector_type(2))) float f32x2;
typedef __attribute__((ext_vector_type(4))) unsigned uint4v;

__device__ __forceinline__ unsigned f2bf_bits(float f) {
  unsigned u = __builtin_bit_cast(unsigned, f);
  return (u + 0x7fffu + ((u >> 16) & 1u)) >> 16;   // RNE, inputs finite
}

__device__ __forceinline__ void async_load16(const void* g, void* l) {
  __builtin_amdgcn_global_load_lds(
      (__attribute__((address_space(1))) void*)g,
      (__attribute__((address_space(3))) void*)l, 16, 0, 0);
}

// ---- prep (single dispatch): xd rows + halo + weight frag-relayout ---------
// Blocks 0..511   : one (n,y) row. Coalesced float2 reads of x, scale by
//                   depth, c-major LDS transpose, coalesced NHWC writes.
// Blocks 512..515 : zero halo rows 0 and 129 of image n.
// Blocks 516..579 : wt2 in MFMA-A-fragment order, K-slot s = cc*9 + tap:
//   gid = o0*147456 + s*4096 + wm*2048 + lane*32 + t*8 + j   (shorts)
//   o = o0*128 + wm*64 + t*16 + (lane&15)
//   cc = s/9; tap = s%9; c = cc*32 + (lane>>4)*8 + j
__global__ __launch_bounds__(256) void prep_all(const float* __restrict__ x,
                                                const float* __restrict__ depth,
                                                const float* __restrict__ w,
                                                short* __restrict__ xd,
                                                short* __restrict__ wt2) {
  const int R = blockIdx.x;

  if (R >= NB * HW + NB) {                  // ---- weight blocks
    int gid = (R - (NB * HW + NB)) * 4608 + threadIdx.x;   // 64 * 4608 = 294912
#pragma unroll
    for (int i = 0; i < 18; ++i, gid += 256) {
      const int j = gid & 7;
      const int t = (gid >> 3) & 3;
      const int lane = (gid >> 5) & 63;
      const int wm = (gid >> 11) & 1;
      const int g2 = gid >> 12;
      const int s = g2 % 36;               // K-slot in conv order: cc*9 + tap
      const int o0 = g2 / 36;
      const int ln = lane & 15, q = lane >> 4;
      const int o = (o0 << 7) + (wm << 6) + (t << 4) + ln;
      const int cc = s / 9;
      const int tap = s % 9;
      const int c = (cc << 5) + (q << 3) + j;
      wt2[gid] = (short)f2bf_bits(w[((size_t)o * C_IN + c) * 9 + tap]);
    }
    return;
  }

  if (R >= NB * HW) {                       // ---- halo-row zero blocks
    const int n = R - NB * HW;
    uint4v* base0 = (uint4v*)(xd + (size_t)n * PADW * PADW * C_IN);
    uint4v* base1 = (uint4v*)(xd + ((size_t)n * PADW + (PADW - 1)) * PADW * C_IN);
    const uint4v z = {0u, 0u, 0u, 0u};
    const int per_row = PADW * C_IN * 2 / 16;   // 2080 uint4 per padded row
    for (int i = threadIdx.x; i < per_row; i += 256) {
      base0[i] = z;
      base1[i] = z;
    }
    return;
  }

  // ---- row-transform blocks
  __shared__ short s[C_IN * PADW];   // c-major: s[c*130 + px]

  const int n = R >> 7, y = R & 127;
  const int tid = threadIdx.x;
  const int lane = tid & 63;
  const int wave = tid >> 6;

  // zero the two edge pixels of this padded row (x=0 and x=129)
  {
    unsigned* row = (unsigned*)(xd + ((size_t)(n * PADW + y + 1) * PADW) * C_IN);
    if (tid < 64) row[tid] = 0u;                              // pixel 0
    else if (tid < 128) row[(size_t)(PADW - 1) * 64 + (tid - 64)] = 0u;  // pixel 129
  }

  // phase 1: read x (float2, coalesced), scale, dword-write to LDS (c-major)
  const f32x2 d2 = *(const f32x2*)(depth + ((size_t)n * HW + y) * HW + 2 * lane);
  const float* xrow = x + (((size_t)n * C_IN) * HW + y) * HW + 2 * lane;
  unsigned* s32 = (unsigned*)s;
#pragma unroll 8
  for (int ci = 0; ci < 32; ++ci) {
    const int c = ci * 4 + wave;
    const f32x2 v = *(const f32x2*)(xrow + (size_t)c * HW * HW);
    s32[c * 65 + lane] = f2bf_bits(v.x * d2.x) | (f2bf_bits(v.y * d2.y) << 16);
  }
  __syncthreads();

  // phase 2: coalesced NHWC write (pixels 1..128 of the padded row)
  const unsigned short* s16 = (const unsigned short*)s;
  unsigned* orow = (unsigned*)(xd + ((size_t)(n * PADW + y + 1) * PADW + 1) * C_IN);
#pragma unroll 8
  for (int i = 0; i < 32; ++i) {
    const int flat = tid + i * 256;      // 0..8191 dwords
    const int px = flat >> 6, cp = flat & 63;
    const unsigned lo = s16[(2 * cp) * PADW + px];
    const unsigned hi = s16[(2 * cp + 1) * PADW + px];
    orow[flat] = lo | (hi << 16);
  }
}

// ---- main MFMA implicit-GEMM conv ------------------------------------------
// Block: 512 threads, 8 waves (2 wm x 4 wn), tile 128(o) x 256(px = 2 rows).
// Wave tile 64(o) x 64(px): acc 4x4 (64 AGPR). K = 1152 as (cc) x (tap).
// Per cc-phase: stage 4row x 130px x 32ch strip (33,280 B, single buffer);
// 9 barrier-free tap steps read it at static ds offsets; a-frags stream from
// wt2 (fragment-major, L2-hot) with ping-pong register prefetch.
__global__ __launch_bounds__(512, 4) void conv_mfma(
    const short* __restrict__ xd, const short* __restrict__ wt2,
    const float* __restrict__ bias, float* __restrict__ out) {
  __shared__ short xbuf[16640];   // [px_strip 520][32 ch]  (33,280 B)

  const int tid = threadIdx.x;
  const int bx = blockIdx.x;            // n*64 + ypair
  const int n = bx >> 6;
  const int y = (bx & 63) << 1;         // first of two output rows
  const int o0b = blockIdx.y;           // o tile (x128)
  const int lane = tid & 63;
  const int wave = tid >> 6;            // 0..7
  const int wm = wave & 1;              // o half
  const int wn = wave >> 1;             // 0..3: (row_sel = wn>>1, px_half = wn&1)
  const int rsel = wn >> 1;
  const int phal = (wn & 1) << 6;
  const int ln = lane & 15, q = lane >> 4;

  // W fragment stream base (shorts): wt2 + o0*147456 + wm*2048 + lane*32
  const short* wbase =
      wt2 + (size_t)o0b * 147456 + (wm << 11) + (lane << 5);

  // X strip staging: strip = padded rows y..y+3, px 0..129, chunks f=0..2079
  // src(f) = strip_base + (f>>2)*128 + cc*32 + (f&3)*8 ; lds(f) = f*8 shorts
  // 512 threads: f = tid + 512k (k<4), tail f = 2048+tid (tid<32)
  const short* xsrc0 = xd + (size_t)(n * PADW + y) * PADW * C_IN +
                       (tid >> 2) * C_IN + (tid & 3) * 8;
  short* xdst0 = xbuf + tid * 8;

  f32x4 acc[4][4] = {};
  short8 areg[2][4];

  auto loadA = [&](int s, int p) {
#pragma unroll
    for (int t = 0; t < 4; ++t)
      areg[p][t] = *(const short8*)(wbase + (size_t)s * 4096 + t * 8);
  };
  auto stageX = [&](int cc) {
    const short* sp = xsrc0 + (cc << 5);
#pragma unroll
    for (int k = 0; k < 4; ++k)
      async_load16(sp + k * 16384, xdst0 + k * 4096);
    if (tid < 32) async_load16(sp + 65536, xdst0 + 16384);  // tail 32 chunks
  };

  loadA(0, 0);
  stageX(0);
  __syncthreads();   // vmcnt(0) drain: xbuf(cc=0) ready

#pragma unroll
  for (int cc = 0; cc < 4; ++cc) {
#pragma unroll
    for (int tap = 0; tap < 9; ++tap) {
      const int s = cc * 9 + tap;
      if (s + 1 < 36) loadA(s + 1, (s + 1) & 1);   // prefetch next a-frags

      const int ti = tap / 3, tj = tap % 3;        // static under unroll
      const int rbase = (rsel + ti) * 130 + phal + tj;

      short8 b[4];
#pragma unroll
      for (int u = 0; u < 4; ++u)
        b[u] = *(const short8*)(xbuf + (rbase + (u << 4) + ln) * 32 + (q << 3));
#pragma unroll
      for (int t = 0; t < 4; ++t)
#pragma unroll
        for (int u = 0; u < 4; ++u)
          acc[t][u] = __builtin_amdgcn_mfma_f32_16x16x32_bf16(
              areg[s & 1][t], b[u], acc[t][u], 0, 0, 0);
    }
    if (cc + 1 < 4) {
      __syncthreads();       // all waves done reading xbuf(cc)
      stageX(cc + 1);
      __syncthreads();       // drain: xbuf(cc+1) ready
    }
  }

  // epilogue: D layout col=lane&15 (pixel), row=q*4+r (o)
  const int yrow = y + rsel;
#pragma unroll
  for (int t = 0; t < 4; ++t) {
    const int ob = (o0b << 7) + (wm << 6) + (t << 4) + (q << 2);
#pragma unroll
    for (int u = 0; u < 4; ++u) {
      const int xcol = phal + (u << 4) + ln;      // 0..127
#pragma unroll
      for (int r = 0; r < 4; ++r) {
        const int o = ob + r;
        out[(((size_t)n * O_OUT + o) * HW + yrow) * HW + xcol] =
            acc[t][u][r] + bias[o];
      }
    }
  }
}

// ---- fallback (only if ws_size is too small): naive direct conv ------------
__global__ void conv_naive(const float* __restrict__ x,
                           const float* __restrict__ depth,
                           const float* __restrict__ w,
                           const float* __restrict__ bias,
                           float* __restrict__ out) {
  const int gid = blockIdx.x * 256 + threadIdx.x;
  if (gid >= NB * O_OUT * HW * HW) return;
  const int xc = gid & 127;
  const int y = (gid >> 7) & 127;
  const int o = (gid >> 14) & 255;
  const int n = gid >> 22;
  float s = bias[o];
  for (int c = 0; c < C_IN; ++c)
    for (int i = 0; i < 3; ++i) {
      const int yy = y + i - 1;
      if (yy < 0 || yy >= HW) continue;
      for (int j = 0; j < 3; ++j) {
        const int xx = xc + j - 1;
        if (xx < 0 || xx >= HW) continue;
        s += w[((o * C_IN + c) * 3 + i) * 3 + j] *
             x[(((size_t)n * C_IN + c) * HW + yy) * HW + xx] *
             depth[((size_t)n * HW + yy) * HW + xx];
      }
    }
  out[gid] = s;
}

extern "C" void kernel_launch(void* const* d_in, const int* in_sizes, int n_in,
                              void* d_out, int out_size, void* d_ws, size_t ws_size,
                              hipStream_t stream) {
  const float* x = (const float*)d_in[0];
  const float* depth = (const float*)d_in[1];
  // d_in[2] = camera_params (unused by reference)
  const float* weight = (const float*)d_in[3];
  const float* bias = (const float*)d_in[4];
  float* out = (float*)d_out;

  const size_t need = XD_BYTES + WT_BYTES;
  if (ws_size < need) {
    conv_naive<<<(NB * O_OUT * HW * HW + 255) / 256, 256, 0, stream>>>(
        x, depth, weight, bias, out);
    return;
  }

  short* xd = (short*)d_ws;
  short* wt2 = (short*)((char*)d_ws + XD_BYTES);

  prep_all<<<NB * HW + NB + 64, 256, 0, stream>>>(x, depth, weight, xd, wt2);
  conv_mfma<<<dim3(NB * HW / 2, 2), 512, 0, stream>>>(xd, wt2, bias, out);
}